// Round 6
// baseline (146.996 us; speedup 1.0000x reference)
//
#include <hip/hip_runtime.h>
#include <stdint.h>

// out = tokens @ W_eff + b_eff, where W_eff folds the BULK_DIM=10 depth
// dimension with closed-form weights w_k = (1/10) * sum_{z=k..10} 1/z.
// (The reference scan is the running mean; averaging over depth gives these.)

static constexpr float FW[10] = {
    0.2928968253968254f, 0.1928968253968254f, 0.1428968253968254f,
    0.1095634920634921f, 0.0845634920634921f, 0.0645634920634921f,
    0.0478968253968254f, 0.0336111111111111f, 0.0211111111111111f,
    0.0100000000000000f};

typedef __attribute__((ext_vector_type(8))) short short8;     // 8 bf16 = 4 VGPR
typedef __attribute__((ext_vector_type(4))) float floatx4;    // 16x16 C/D frag
typedef __attribute__((ext_vector_type(16))) float floatx16;  // 32x32 C/D frag

// round-to-nearest fp32->bf16, pack two into one uint via v_perm_b32
__device__ inline unsigned int bf16pack2(float hi, float lo) {
    unsigned int uh = __float_as_uint(hi) + 0x8000u;
    unsigned int ul = __float_as_uint(lo) + 0x8000u;
    return __builtin_amdgcn_perm(uh, ul, 0x07060302u);  // {hi[31:16], lo[31:16]}
}

#define LDS_AS(p) ((__attribute__((address_space(3))) unsigned int*)(p))
#define GLB_AS(p) ((const __attribute__((address_space(1))) unsigned int*)(p))

// ---------------------------------------------------------------------------
// Merged prep kernel (one launch, block-id partitioned):
//   blocks [0,512):    fold_w  W_eff^T[n][k] bf16, n-major (32k x 64n tiles)
//   block  512:        fold_b  b_eff fp32
//   blocks [513,4609): cvt     tokens fp32 -> bf16 (8 elems/thread)
// All HBM-bound; combined ~94 MB => ~15-16 us.
// ---------------------------------------------------------------------------
__global__ __launch_bounds__(256) void prep(const float* __restrict__ W,
                                            const float* __restrict__ tokens,
                                            const float* __restrict__ b,
                                            unsigned short* __restrict__ Wt,
                                            float* __restrict__ beff,
                                            uint4* __restrict__ Ab,
                                            int do_cvt) {
    __shared__ float T[32 * 65];
    const int t = threadIdx.x;
    const int bid = blockIdx.x;

    if (bid < 512) {  // ---- fold_w
        const int n0 = (bid & 15) * 64;
        const int k0 = (bid >> 4) * 32;
#pragma unroll
        for (int s = 0; s < 2; ++s) {
            int slot = s * 256 + t;
            int r = slot >> 4;              // k-local 0..31
            int c4 = (slot & 15) * 4;       // n-local float4
            const float4* src = (const float4*)(W + (size_t)(k0 + r) * 10240 + n0 + c4);
            float4 acc = {0.f, 0.f, 0.f, 0.f};
#pragma unroll
            for (int j = 0; j < 10; ++j) {
                float4 v = src[j * 256];
                acc.x += FW[j] * v.x; acc.y += FW[j] * v.y;
                acc.z += FW[j] * v.z; acc.w += FW[j] * v.w;
            }
            T[r * 65 + c4 + 0] = acc.x;
            T[r * 65 + c4 + 1] = acc.y;
            T[r * 65 + c4 + 2] = acc.z;
            T[r * 65 + c4 + 3] = acc.w;
        }
        __syncthreads();
#pragma unroll
        for (int s = 0; s < 2; ++s) {
            int slot = s * 256 + t;
            int nl = slot >> 3;             // n-local 0..63
            int k4 = (slot & 7) * 4;        // k-local group of 4
            float f0 = T[(k4 + 0) * 65 + nl];
            float f1 = T[(k4 + 1) * 65 + nl];
            float f2 = T[(k4 + 2) * 65 + nl];
            float f3 = T[(k4 + 3) * 65 + nl];
            uint2 p;
            p.x = bf16pack2(f1, f0);
            p.y = bf16pack2(f3, f2);
            *(uint2*)(Wt + (size_t)(n0 + nl) * 1024 + k0 + k4) = p;
        }
        return;
    }
    if (bid == 512) {  // ---- fold_b
        const float4* src = (const float4*)b + t;
        float4 acc = {0.f, 0.f, 0.f, 0.f};
#pragma unroll
        for (int j = 0; j < 10; ++j) {
            float4 v = src[j * 256];
            acc.x += FW[j] * v.x; acc.y += FW[j] * v.y;
            acc.z += FW[j] * v.z; acc.w += FW[j] * v.w;
        }
        ((float4*)beff)[t] = acc;
        return;
    }
    if (do_cvt) {  // ---- cvt tokens -> bf16
        size_t i = (size_t)(bid - 513) * 256 + t;
        const float4* src = (const float4*)tokens + i * 2;
        float4 a0 = src[0], a1 = src[1];
        uint4 p;
        p.x = bf16pack2(a0.y, a0.x);
        p.y = bf16pack2(a0.w, a0.z);
        p.z = bf16pack2(a1.y, a1.x);
        p.w = bf16pack2(a1.w, a1.z);
        Ab[i] = p;
    }
}

// ---------------------------------------------------------------------------
// GEMM: C[8192][1024] = Ab(bf16) @ Weff^T + b_eff
// Tile 64(M) x 128(N), 4 waves in 1x4: wave w = rows 0..63, cols w*32..+32,
// 2 acc tiles of mfma_f32_32x32x16_bf16 (32 acc VGPRs).
// Occupancy: grid (128,8) = 1024 blocks = 4 blocks/CU = 4 waves/SIMD
// (R4/R5 lesson: 2 waves/SIMD was latency-bound; BW floors all << observed).
// A: LDS double-buffer 2x8KB, global_load_lds w=16, XOR swizzle
//    slot = m*8 + (c ^ (m&7)) -> ds_read_b128 2-way (free).
// B: NO LDS - per-lane 16B global loads; B K-tile = 16KB, L1-resident,
//    shared by the 4 co-resident blocks (same bn); separate VMEM pipe.
// Grid x = M-tile: id%8 = bm%8 pins A stripes per XCD (A+B = 4MB = L2).
// ---------------------------------------------------------------------------
__global__ __launch_bounds__(256) void gemm32(const unsigned short* __restrict__ Ab,
                                              const unsigned short* __restrict__ Wt,
                                              const float* __restrict__ beff,
                                              float* __restrict__ C) {
    __shared__ __align__(16) unsigned char As[2][8192];  // 64 rows x 8 chunks x 16B

    const int t = threadIdx.x;
    const int lane = t & 63;
    const int w = t >> 6;              // wave 0..3 = n-strip
    const int l31 = lane & 31;
    const int khalf = lane >> 5;       // 0/1: k-offset 0 or 8 within K=16
    const int bm = blockIdx.x * 64;    // x fastest -> id%8 = M-tile%8 (XCD pin)
    const int bn = blockIdx.y * 128;

    floatx16 acc[2];
#pragma unroll
    for (int i = 0; i < 2; ++i)
#pragma unroll
        for (int r = 0; r < 16; ++r) acc[i][r] = 0.f;

    const char* Abase = (const char*)Ab + (size_t)bm * 2048;
    // this lane's B row pointer (col bn + w*32 + l31), khalf baked in
    const char* Bp = (const char*)Wt + (size_t)(bn + w * 32 + l31) * 2048 + khalf * 16;

    const int sI = w * 2;  // this wave's 2 staging row-groups (of 8 total)

    // prologue: stage A tile 0 into buffer 0 (512 slots of 16B)
#pragma unroll
    for (int i = 0; i < 2; ++i) {
        int I = sI + i;
        int slot = I * 64 + lane;       // 0..511
        int m = slot >> 3;              // row 0..63
        int c = (slot & 7) ^ (m & 7);   // XOR swizzle
        size_t off = (size_t)m * 2048 + c * 16;
        __builtin_amdgcn_global_load_lds(GLB_AS(Abase + off), LDS_AS(As[0] + I * 1024), 16, 0, 0);
    }

#pragma unroll
    for (int kt = 0; kt < 16; ++kt) {
        __syncthreads();  // A tile kt ready (prefetched a full compute phase ago)

        if (kt < 15) {    // prefetch A tile kt+1 into the other buffer
            int buf = (kt + 1) & 1;
#pragma unroll
            for (int i = 0; i < 2; ++i) {
                int I = sI + i;
                int slot = I * 64 + lane;
                int m = slot >> 3;
                int c = (slot & 7) ^ (m & 7);
                size_t off = (size_t)m * 2048 + (size_t)(kt + 1) * 128 + c * 16;
                __builtin_amdgcn_global_load_lds(GLB_AS(Abase + off), LDS_AS(As[buf] + I * 1024), 16, 0, 0);
            }
        }

        const unsigned char* Acur = As[kt & 1];
#pragma unroll
        for (int kk = 0; kk < 4; ++kk) {
            int c = kk * 2 + khalf;     // logical chunk 0..7
            // B fragment: direct global (L1/L2), 16B per lane
            short8 bf = *(const short8*)(Bp + kt * 128 + kk * 32);
            short8 af[2];
#pragma unroll
            for (int tm = 0; tm < 2; ++tm) {
                int m = tm * 32 + l31;
                int slot = m * 8 + (c ^ (m & 7));
                af[tm] = *(const short8*)(Acur + slot * 16);
            }
#pragma unroll
            for (int tm = 0; tm < 2; ++tm)
                acc[tm] = __builtin_amdgcn_mfma_f32_32x32x16_bf16(af[tm], bf, acc[tm], 0, 0, 0);
        }
    }

    // epilogue: col = lane&31, row = (reg&3) + 8*(reg>>2) + 4*(lane>>5)
    {
        int col = bn + w * 32 + l31;
        float bias = beff[col];
#pragma unroll
        for (int tm = 0; tm < 2; ++tm) {
            int rbase = bm + tm * 32 + 4 * khalf;
#pragma unroll
            for (int r = 0; r < 16; ++r) {
                int row = rbase + (r & 3) + 8 * (r >> 2);
                C[(size_t)row * 1024 + col] = acc[tm][r] + bias;
            }
        }
    }
}

// ---------------------------------------------------------------------------
// Fallback GEMM (fp32 A converted in-kernel) for small ws_size.
// ---------------------------------------------------------------------------
__global__ __launch_bounds__(256) void gemm_fb(const float* __restrict__ A,
                                               const unsigned short* __restrict__ Wt,
                                               const float* __restrict__ beff,
                                               float* __restrict__ C) {
    __shared__ __align__(16) unsigned short As[128 * 72];
    __shared__ __align__(16) unsigned char Bs[16384];

    const int t = threadIdx.x;
    const int lane = t & 63;
    const int w = t >> 6;
    const int quad = lane >> 4;
    const int l15 = lane & 15;
    const int wm = (w & 1) * 64;
    const int wn = (w >> 1) * 64;
    const int bm = blockIdx.y * 128;
    const int bn = blockIdx.x * 128;

    floatx4 acc[4][4];
#pragma unroll
    for (int i = 0; i < 4; ++i)
#pragma unroll
        for (int j = 0; j < 4; ++j) acc[i][j] = (floatx4){0.f, 0.f, 0.f, 0.f};

    const int ar = t >> 4;
    const int ac4 = (t & 15) * 4;
    const float* Abase = A + (size_t)(bm + ar) * 1024 + ac4;
    const char* WtB = (const char*)Wt;

    for (int k0 = 0; k0 < 1024; k0 += 64) {
#pragma unroll
        for (int i = 0; i < 4; ++i) {
            int I = w * 4 + i;
            int slot = I * 64 + lane;
            int nl = slot >> 3;
            int c = (slot & 7) ^ (nl & 7);
            const char* g = WtB + (size_t)(bn + nl) * 2048 + k0 * 2 + c * 16;
            __builtin_amdgcn_global_load_lds(GLB_AS(g), LDS_AS(Bs + I * 1024), 16, 0, 0);
        }
        float4 av[8];
#pragma unroll
        for (int s = 0; s < 8; ++s)
            av[s] = *(const float4*)(Abase + (size_t)(s * 16) * 1024 + k0);
#pragma unroll
        for (int s = 0; s < 8; ++s) {
            uint2 p;
            p.x = bf16pack2(av[s].y, av[s].x);
            p.y = bf16pack2(av[s].w, av[s].z);
            *(uint2*)((char*)As + (size_t)(s * 16 + ar) * 144 + ac4 * 2) = p;
        }
        __syncthreads();
#pragma unroll
        for (int kk = 0; kk < 2; ++kk) {
            short8 af[4], bf[4];
#pragma unroll
            for (int tm = 0; tm < 4; ++tm) {
                int m = wm + tm * 16 + l15;
                af[tm] = *(const short8*)((const char*)As + (size_t)m * 144 + kk * 64 + quad * 16);
            }
#pragma unroll
            for (int tn = 0; tn < 4; ++tn) {
                int n = wn + tn * 16 + l15;
                int c = kk * 4 + quad;
                int slot = n * 8 + (c ^ (n & 7));
                bf[tn] = *(const short8*)(Bs + slot * 16);
            }
#pragma unroll
            for (int tm = 0; tm < 4; ++tm)
#pragma unroll
                for (int tn = 0; tn < 4; ++tn)
                    acc[tm][tn] = __builtin_amdgcn_mfma_f32_16x16x32_bf16(
                        af[tm], bf[tn], acc[tm][tn], 0, 0, 0);
        }
        __syncthreads();
    }
#pragma unroll
    for (int tn = 0; tn < 4; ++tn) {
        int col = bn + wn + tn * 16 + l15;
        float bias = beff[col];
#pragma unroll
        for (int tm = 0; tm < 4; ++tm) {
            int row0 = bm + wm + tm * 16 + quad * 4;
#pragma unroll
            for (int r = 0; r < 4; ++r)
                C[(size_t)(row0 + r) * 1024 + col] = acc[tm][tn][r] + bias;
        }
    }
}

extern "C" void kernel_launch(void* const* d_in, const int* in_sizes, int n_in,
                              void* d_out, int out_size, void* d_ws, size_t ws_size,
                              hipStream_t stream) {
    const float* tokens = (const float*)d_in[0];  // (4,2048,1024) fp32
    const float* W      = (const float*)d_in[1];  // (1024, 10240) fp32
    const float* b      = (const float*)d_in[2];  // (10240,) fp32
    float* out = (float*)d_out;                   // (4,2048,1024) fp32

    unsigned short* Wt = (unsigned short*)d_ws;                       // 2 MB bf16
    float* beff = (float*)((char*)d_ws + 2097152);                    // 4 KB fp32
    unsigned short* Ab = (unsigned short*)((char*)d_ws + 2101248);    // 16.8 MB bf16

    const int big_ws = ws_size >= 2101248 + (size_t)8192 * 1024 * 2;

    if (big_ws) {
        prep<<<513 + 4096, 256, 0, stream>>>(W, tokens, b, Wt, beff, (uint4*)Ab, 1);
        gemm32<<<dim3(128, 8), 256, 0, stream>>>(Ab, Wt, beff, out);
    } else {
        prep<<<513, 256, 0, stream>>>(W, tokens, b, Wt, beff, (uint4*)Ab, 0);
        gemm_fb<<<dim3(8, 64), 256, 0, stream>>>(tokens, Wt, beff, out);
    }
}

// Round 7
// 140.746 us; speedup vs baseline: 1.0444x; 1.0444x over previous
//
#include <hip/hip_runtime.h>
#include <stdint.h>

// out = tokens @ W_eff + b_eff, where W_eff folds the BULK_DIM=10 depth
// dimension with closed-form weights w_k = (1/10) * sum_{z=k..10} 1/z.
// (The reference scan is the running mean; averaging over depth gives these.)

static constexpr float FW[10] = {
    0.2928968253968254f, 0.1928968253968254f, 0.1428968253968254f,
    0.1095634920634921f, 0.0845634920634921f, 0.0645634920634921f,
    0.0478968253968254f, 0.0336111111111111f, 0.0211111111111111f,
    0.0100000000000000f};

typedef __attribute__((ext_vector_type(8))) short short8;     // 8 bf16 = 4 VGPR
typedef __attribute__((ext_vector_type(16))) float floatx16;  // 32x32 C/D frag

// round-to-nearest fp32->bf16, pack two into one uint via v_perm_b32
__device__ inline unsigned int bf16pack2(float hi, float lo) {
    unsigned int uh = __float_as_uint(hi) + 0x8000u;
    unsigned int ul = __float_as_uint(lo) + 0x8000u;
    return __builtin_amdgcn_perm(uh, ul, 0x07060302u);  // {hi[31:16], lo[31:16]}
}

#define LDS_AS(p) ((__attribute__((address_space(3))) unsigned int*)(p))
#define GLB_AS(p) ((const __attribute__((address_space(1))) unsigned int*)(p))

// ---------------------------------------------------------------------------
// Prep (one launch): blocks [0,512) fold_w -> W_eff^T bf16 n-major;
// block 512 fold_b. 44 MB total => ~8 us. (cvt removed: conversion now
// happens inside the GEMM's A-staging — R6 post-mortem.)
// ---------------------------------------------------------------------------
__global__ __launch_bounds__(256) void prep(const float* __restrict__ W,
                                            const float* __restrict__ b,
                                            unsigned short* __restrict__ Wt,
                                            float* __restrict__ beff) {
    __shared__ float T[32 * 65];
    const int t = threadIdx.x;
    const int bid = blockIdx.x;

    if (bid < 512) {  // ---- fold_w: 32(k) x 64(n) tile
        const int n0 = (bid & 15) * 64;
        const int k0 = (bid >> 4) * 32;
#pragma unroll
        for (int s = 0; s < 2; ++s) {
            int slot = s * 256 + t;
            int r = slot >> 4;              // k-local 0..31
            int c4 = (slot & 15) * 4;       // n-local float4
            const float4* src = (const float4*)(W + (size_t)(k0 + r) * 10240 + n0 + c4);
            float4 acc = {0.f, 0.f, 0.f, 0.f};
#pragma unroll
            for (int j = 0; j < 10; ++j) {
                float4 v = src[j * 256];
                acc.x += FW[j] * v.x; acc.y += FW[j] * v.y;
                acc.z += FW[j] * v.z; acc.w += FW[j] * v.w;
            }
            T[r * 65 + c4 + 0] = acc.x;
            T[r * 65 + c4 + 1] = acc.y;
            T[r * 65 + c4 + 2] = acc.z;
            T[r * 65 + c4 + 3] = acc.w;
        }
        __syncthreads();
#pragma unroll
        for (int s = 0; s < 2; ++s) {
            int slot = s * 256 + t;
            int nl = slot >> 3;             // n-local 0..63
            int k4 = (slot & 7) * 4;        // k-local group of 4
            float f0 = T[(k4 + 0) * 65 + nl];
            float f1 = T[(k4 + 1) * 65 + nl];
            float f2 = T[(k4 + 2) * 65 + nl];
            float f3 = T[(k4 + 3) * 65 + nl];
            uint2 p;
            p.x = bf16pack2(f1, f0);
            p.y = bf16pack2(f3, f2);
            *(uint2*)(Wt + (size_t)(n0 + nl) * 1024 + k0 + k4) = p;
        }
        return;
    }
    // ---- fold_b
    const float4* src = (const float4*)b + t;
    float4 acc = {0.f, 0.f, 0.f, 0.f};
#pragma unroll
    for (int j = 0; j < 10; ++j) {
        float4 v = src[j * 256];
        acc.x += FW[j] * v.x; acc.y += FW[j] * v.y;
        acc.z += FW[j] * v.z; acc.w += FW[j] * v.w;
    }
    ((float4*)beff)[t] = acc;
}

// ---------------------------------------------------------------------------
// Merged GEMM: C[8192][1024] = cvt_bf16(A_fp32) @ Weff^T + b_eff
// 128x128 tile, 4 waves 2x2, each wave 64x64 = 2x2 mfma_f32_32x32x16_bf16,
// BK=64. Per kt pipeline (all waitcnt drains a full phase old):
//   repack av -> ds_write As(kt)            (A fp32->bf16 in-register)
//   barrier A   (drains B-glds(kt), issued one iteration ago)
//   issue A-loads(kt+1) fp32 -> av          (VGPR loads float through barriers)
//   issue B-glds(kt+1) -> Bs[(kt+1)&1]      (double-buffered)
//   compute(kt): 16 ds_read_b128 + 16 MFMA
//   barrier B   (drains the loads issued ~350 cyc earlier)
// A LDS: 16 KB single buffer (WAR protected by barrier B).
// XOR swizzle slot = row*8 + (chunk ^ (row&7)) for both operands.
// Grid (64,8), x = M-tile: id%8 = bm%8 pins A fp32 stripes per XCD ->
// A HBM-fetched once (33.5 MB), L2-served for the 8 bn re-reads
// (R1's 132 MB / 47 us came from missing this pin).
// ---------------------------------------------------------------------------
__global__ __launch_bounds__(256) void gemm_m(const float* __restrict__ A,
                                              const unsigned short* __restrict__ Wt,
                                              const float* __restrict__ beff,
                                              float* __restrict__ C) {
    __shared__ __align__(16) unsigned char As[16384];     // 128 rows x 8 chunks x 16B
    __shared__ __align__(16) unsigned char Bs[2][16384];

    const int t = threadIdx.x;
    const int lane = t & 63;
    const int w = t >> 6;
    const int l31 = lane & 31;
    const int khalf = lane >> 5;       // 0/1: k-offset 0 or 8 within K=16
    const int wm = (w & 1) * 64;
    const int wn = (w >> 1) * 64;
    const int bm = blockIdx.x * 128;   // x fastest -> id%8 = M-tile%8 (XCD pin)
    const int bn = blockIdx.y * 128;

    floatx16 acc[2][2];
#pragma unroll
    for (int i = 0; i < 2; ++i)
#pragma unroll
        for (int j = 0; j < 2; ++j)
#pragma unroll
            for (int r = 0; r < 16; ++r) acc[i][j][r] = 0.f;

    // A staging map: thread -> (row ar in 16-row sweep, float4 col ac4)
    const int ar = t >> 4;               // 0..15
    const int ac4 = (t & 15) * 4;        // 0,4,...,60
    const int c_log = ac4 >> 3;          // logical 16B chunk 0..7
    const int halfo = (ac4 >> 2) & 1;    // 8B half within chunk
    const float* Ap = A + (size_t)(bm + ar) * 1024 + ac4;
    const char* Bbase = (const char*)Wt + (size_t)bn * 2048;

    // prologue: A(0) into regs, B(0) into Bs[0]
    float4 av[8];
#pragma unroll
    for (int s = 0; s < 8; ++s)
        av[s] = *(const float4*)(Ap + (size_t)(s * 16) * 1024);
#pragma unroll
    for (int i = 0; i < 4; ++i) {
        int I = w * 4 + i;
        int slot = I * 64 + lane;
        int n = slot >> 3;
        int c = (slot & 7) ^ (n & 7);
        __builtin_amdgcn_global_load_lds(GLB_AS(Bbase + (size_t)n * 2048 + c * 16),
                                         LDS_AS(Bs[0] + I * 1024), 16, 0, 0);
    }

#pragma unroll
    for (int kt = 0; kt < 16; ++kt) {
        // stage A(kt): repack fp32->bf16, swizzled ds_write_b64
#pragma unroll
        for (int s = 0; s < 8; ++s) {
            float4 v = av[s];
            uint2 p;
            p.x = bf16pack2(v.y, v.x);
            p.y = bf16pack2(v.w, v.z);
            int m = s * 16 + ar;
            int slot = m * 8 + (c_log ^ (m & 7));
            *(uint2*)(As + slot * 16 + halfo * 8) = p;
        }
        __syncthreads();  // barrier A

        if (kt < 15) {
            // A-loads(kt+1): plain VGPR loads — no drain at barriers
#pragma unroll
            for (int s = 0; s < 8; ++s)
                av[s] = *(const float4*)(Ap + (size_t)(s * 16) * 1024 + (kt + 1) * 64);
            // B-glds(kt+1) into the other buffer
#pragma unroll
            for (int i = 0; i < 4; ++i) {
                int I = w * 4 + i;
                int slot = I * 64 + lane;
                int n = slot >> 3;
                int c = (slot & 7) ^ (n & 7);
                __builtin_amdgcn_global_load_lds(
                    GLB_AS(Bbase + (size_t)n * 2048 + (size_t)(kt + 1) * 128 + c * 16),
                    LDS_AS(Bs[(kt + 1) & 1] + I * 1024), 16, 0, 0);
            }
        }

        const unsigned char* Bcur = Bs[kt & 1];
#pragma unroll
        for (int kk = 0; kk < 4; ++kk) {
            int c = kk * 2 + khalf;
            short8 af[2], bf[2];
#pragma unroll
            for (int tm = 0; tm < 2; ++tm) {
                int m = wm + tm * 32 + l31;
                int slot = m * 8 + (c ^ (m & 7));
                af[tm] = *(const short8*)(As + slot * 16);
            }
#pragma unroll
            for (int tn = 0; tn < 2; ++tn) {
                int n = wn + tn * 32 + l31;
                int slot = n * 8 + (c ^ (n & 7));
                bf[tn] = *(const short8*)(Bcur + slot * 16);
            }
#pragma unroll
            for (int tm = 0; tm < 2; ++tm)
#pragma unroll
                for (int tn = 0; tn < 2; ++tn)
                    acc[tm][tn] = __builtin_amdgcn_mfma_f32_32x32x16_bf16(
                        af[tm], bf[tn], acc[tm][tn], 0, 0, 0);
        }
        __syncthreads();  // barrier B
    }

    // epilogue: col = lane&31, row = (reg&3) + 8*(reg>>2) + 4*(lane>>5)
#pragma unroll
    for (int tn = 0; tn < 2; ++tn) {
        int col = bn + wn + tn * 32 + l31;
        float bias = beff[col];
#pragma unroll
        for (int tm = 0; tm < 2; ++tm) {
            int rbase = bm + wm + tm * 32 + 4 * khalf;
#pragma unroll
            for (int r = 0; r < 16; ++r) {
                int row = rbase + (r & 3) + 8 * (r >> 2);
                C[(size_t)row * 1024 + col] = acc[tm][tn][r] + bias;
            }
        }
    }
}

extern "C" void kernel_launch(void* const* d_in, const int* in_sizes, int n_in,
                              void* d_out, int out_size, void* d_ws, size_t ws_size,
                              hipStream_t stream) {
    const float* tokens = (const float*)d_in[0];  // (4,2048,1024) fp32
    const float* W      = (const float*)d_in[1];  // (1024, 10240) fp32
    const float* b      = (const float*)d_in[2];  // (10240,) fp32
    float* out = (float*)d_out;                   // (4,2048,1024) fp32

    unsigned short* Wt = (unsigned short*)d_ws;     // 2 MB bf16
    float* beff = (float*)((char*)d_ws + 2097152);  // 4 KB fp32

    prep<<<513, 256, 0, stream>>>(W, b, Wt, beff);
    gemm_m<<<dim3(64, 8), 256, 0, stream>>>(tokens, Wt, beff, out);
}

// Round 8
// 129.496 us; speedup vs baseline: 1.1351x; 1.0869x over previous
//
#include <hip/hip_runtime.h>
#include <stdint.h>

// out = tokens @ W_eff + b_eff, where W_eff folds the BULK_DIM=10 depth
// dimension with closed-form weights w_k = (1/10) * sum_{z=k..10} 1/z.
// (The reference scan is the running mean; averaging over depth gives these.)

static constexpr float FW[10] = {
    0.2928968253968254f, 0.1928968253968254f, 0.1428968253968254f,
    0.1095634920634921f, 0.0845634920634921f, 0.0645634920634921f,
    0.0478968253968254f, 0.0336111111111111f, 0.0211111111111111f,
    0.0100000000000000f};

typedef __attribute__((ext_vector_type(8))) short short8;     // 8 bf16 = 4 VGPR
typedef __attribute__((ext_vector_type(4))) float floatx4;    // 16x16 C/D frag
typedef __attribute__((ext_vector_type(16))) float floatx16;  // 32x32 C/D frag

// round-to-nearest fp32->bf16, pack two into one uint via v_perm_b32
__device__ inline unsigned int bf16pack2(float hi, float lo) {
    unsigned int uh = __float_as_uint(hi) + 0x8000u;
    unsigned int ul = __float_as_uint(lo) + 0x8000u;
    return __builtin_amdgcn_perm(uh, ul, 0x07060302u);  // {hi[31:16], lo[31:16]}
}

#define LDS_AS(p) ((__attribute__((address_space(3))) unsigned int*)(p))
#define GLB_AS(p) ((const __attribute__((address_space(1))) unsigned int*)(p))

// ---------------------------------------------------------------------------
// Merged prep kernel (one launch, block-id partitioned):
//   blocks [0,512):    fold_w  W_eff^T[n][k] bf16, n-major (32k x 64n tiles)
//   block  512:        fold_b  b_eff fp32
//   blocks [513,4609): cvt     tokens fp32 -> bf16, XCD-ALIGNED: block with
//     hw id%8 == x writes only rows r with (r/128)%8 == x — the same XCD
//     whose gemm blocks will read them (gemm grid x = M-tile, id%8 = tile%8).
//     Ab stripe (2.1 MB/XCD) stays dirty in that XCD's 4 MB L2 -> gemm A
//     reads are L2 hits; saves ~33 MB HBM round-trip.
// ---------------------------------------------------------------------------
__global__ __launch_bounds__(256) void prep(const float* __restrict__ W,
                                            const float* __restrict__ tokens,
                                            const float* __restrict__ b,
                                            unsigned short* __restrict__ Wt,
                                            float* __restrict__ beff,
                                            uint4* __restrict__ Ab,
                                            int do_cvt) {
    __shared__ float T[32 * 65];
    const int t = threadIdx.x;
    const int bid = blockIdx.x;

    if (bid < 512) {  // ---- fold_w
        const int n0 = (bid & 15) * 64;
        const int k0 = (bid >> 4) * 32;
#pragma unroll
        for (int s = 0; s < 2; ++s) {
            int slot = s * 256 + t;
            int r = slot >> 4;              // k-local 0..31
            int c4 = (slot & 15) * 4;       // n-local float4
            const float4* src = (const float4*)(W + (size_t)(k0 + r) * 10240 + n0 + c4);
            float4 acc = {0.f, 0.f, 0.f, 0.f};
#pragma unroll
            for (int j = 0; j < 10; ++j) {
                float4 v = src[j * 256];
                acc.x += FW[j] * v.x; acc.y += FW[j] * v.y;
                acc.z += FW[j] * v.z; acc.w += FW[j] * v.w;
            }
            T[r * 65 + c4 + 0] = acc.x;
            T[r * 65 + c4 + 1] = acc.y;
            T[r * 65 + c4 + 2] = acc.z;
            T[r * 65 + c4 + 3] = acc.w;
        }
        __syncthreads();
#pragma unroll
        for (int s = 0; s < 2; ++s) {
            int slot = s * 256 + t;
            int nl = slot >> 3;             // n-local 0..63
            int k4 = (slot & 7) * 4;        // k-local group of 4
            float f0 = T[(k4 + 0) * 65 + nl];
            float f1 = T[(k4 + 1) * 65 + nl];
            float f2 = T[(k4 + 2) * 65 + nl];
            float f3 = T[(k4 + 3) * 65 + nl];
            uint2 p;
            p.x = bf16pack2(f1, f0);
            p.y = bf16pack2(f3, f2);
            *(uint2*)(Wt + (size_t)(n0 + nl) * 1024 + k0 + k4) = p;
        }
        return;
    }
    if (bid == 512) {  // ---- fold_b
        const float4* src = (const float4*)b + t;
        float4 acc = {0.f, 0.f, 0.f, 0.f};
#pragma unroll
        for (int j = 0; j < 10; ++j) {
            float4 v = src[j * 256];
            acc.x += FW[j] * v.x; acc.y += FW[j] * v.y;
            acc.z += FW[j] * v.z; acc.w += FW[j] * v.w;
        }
        ((float4*)beff)[t] = acc;
        return;
    }
    if (do_cvt) {  // ---- cvt tokens -> bf16, XCD-aligned row mapping
        int u = bid - 513;                 // 0..4095
        int x = (u + 1) & 7;               // == bid & 7 == this block's XCD
        int q = u >> 3;                    // 0..511: index within XCD class
        int j = q >> 6;                    // 0..7: which of this XCD's m-tiles
        int p = q & 63;                    // 0..63: row-pair within tile
        int r0 = 128 * (x + 8 * j) + 2 * p; // first of 2 rows
        size_t i = (size_t)r0 * 128 + t;   // uint4 index (128 uint4 per row)
        const float4* src = (const float4*)tokens + i * 2;
        float4 a0 = src[0], a1 = src[1];
        uint4 pk;
        pk.x = bf16pack2(a0.y, a0.x);
        pk.y = bf16pack2(a0.w, a0.z);
        pk.z = bf16pack2(a1.y, a1.x);
        pk.w = bf16pack2(a1.w, a1.z);
        Ab[i] = pk;
    }
}

// ---------------------------------------------------------------------------
// GEMM: C[8192][1024] = Ab(bf16) @ Weff^T + b_eff
// 128x128 tile, 4 waves 2x2, each wave 64x64 = 2x2 of mfma_f32_32x32x16_bf16.
// BK=64, double-buffered LDS (2 x 16KB per operand, 2 blocks/CU).
// Per iter: barrier -> issue prefetch(kt+1) -> compute(kt); the vmcnt(0)
// drain before the next barrier waits on loads a full compute phase old.
// XOR swizzle slot = row*8 + (chunk ^ (row&7)); fragment ds_read_b128 runs
// at the measured b128 ceiling (12 cyc — R7 analysis: the +4 "conflict"
// cycles are inherent to b128 width, not fixable by swizzle).
// Grid (64,8), x = M-tile: id%8 = M-tile%8 pins A stripes per XCD.
// ---------------------------------------------------------------------------
__global__ __launch_bounds__(256) void gemm32(const unsigned short* __restrict__ Ab,
                                              const unsigned short* __restrict__ Wt,
                                              const float* __restrict__ beff,
                                              float* __restrict__ C) {
    __shared__ __align__(16) unsigned char As[2][16384];  // 128 rows x 8 chunks x 16B
    __shared__ __align__(16) unsigned char Bs[2][16384];

    const int t = threadIdx.x;
    const int lane = t & 63;
    const int w = t >> 6;
    const int l31 = lane & 31;
    const int khalf = lane >> 5;       // 0/1: k-offset 0 or 8 within K=16
    const int wm = (w & 1) * 64;
    const int wn = (w >> 1) * 64;
    const int bm = blockIdx.x * 128;   // x fastest -> id%8 = M-tile%8 (XCD pin)
    const int bn = blockIdx.y * 128;

    floatx16 acc[2][2];
#pragma unroll
    for (int i = 0; i < 2; ++i)
#pragma unroll
        for (int j = 0; j < 2; ++j)
#pragma unroll
            for (int r = 0; r < 16; ++r) acc[i][j][r] = 0.f;

    const char* Abase = (const char*)Ab + (size_t)bm * 2048;
    const char* Bbase = (const char*)Wt + (size_t)bn * 2048;

    const int sI = w * 4;  // this wave's staging row-groups

    // prologue: stage tile 0 into buffer 0
#pragma unroll
    for (int i = 0; i < 4; ++i) {
        int I = sI + i;
        int slot = I * 64 + lane;
        int m = slot >> 3;
        int c = (slot & 7) ^ (m & 7);
        size_t off = (size_t)m * 2048 + c * 16;
        __builtin_amdgcn_global_load_lds(GLB_AS(Abase + off), LDS_AS(As[0] + I * 1024), 16, 0, 0);
        __builtin_amdgcn_global_load_lds(GLB_AS(Bbase + off), LDS_AS(Bs[0] + I * 1024), 16, 0, 0);
    }

#pragma unroll
    for (int kt = 0; kt < 16; ++kt) {
        __syncthreads();  // tile kt staged (prefetched a full compute phase ago)

        if (kt < 15) {    // prefetch tile kt+1 into the other buffer
            int buf = (kt + 1) & 1;
#pragma unroll
            for (int i = 0; i < 4; ++i) {
                int I = sI + i;
                int slot = I * 64 + lane;
                int m = slot >> 3;
                int c = (slot & 7) ^ (m & 7);
                size_t off = (size_t)m * 2048 + (size_t)(kt + 1) * 128 + c * 16;
                __builtin_amdgcn_global_load_lds(GLB_AS(Abase + off), LDS_AS(As[buf] + I * 1024), 16, 0, 0);
                __builtin_amdgcn_global_load_lds(GLB_AS(Bbase + off), LDS_AS(Bs[buf] + I * 1024), 16, 0, 0);
            }
        }

        const unsigned char* Acur = As[kt & 1];
        const unsigned char* Bcur = Bs[kt & 1];
#pragma unroll
        for (int kk = 0; kk < 4; ++kk) {
            int c = kk * 2 + khalf;        // logical chunk 0..7
            short8 af[2], bf[2];
#pragma unroll
            for (int tm = 0; tm < 2; ++tm) {
                int m = wm + tm * 32 + l31;
                int slot = m * 8 + (c ^ (m & 7));
                af[tm] = *(const short8*)(Acur + slot * 16);
            }
#pragma unroll
            for (int tn = 0; tn < 2; ++tn) {
                int n = wn + tn * 32 + l31;
                int slot = n * 8 + (c ^ (n & 7));
                bf[tn] = *(const short8*)(Bcur + slot * 16);
            }
#pragma unroll
            for (int tm = 0; tm < 2; ++tm)
#pragma unroll
                for (int tn = 0; tn < 2; ++tn)
                    acc[tm][tn] = __builtin_amdgcn_mfma_f32_32x32x16_bf16(
                        af[tm], bf[tn], acc[tm][tn], 0, 0, 0);
        }
    }

    // epilogue: col = lane&31, row = (reg&3) + 8*(reg>>2) + 4*(lane>>5)
#pragma unroll
    for (int tn = 0; tn < 2; ++tn) {
        int col = bn + wn + tn * 32 + l31;
        float bias = beff[col];
#pragma unroll
        for (int tm = 0; tm < 2; ++tm) {
            int rbase = bm + wm + tm * 32 + 4 * khalf;
#pragma unroll
            for (int r = 0; r < 16; ++r) {
                int row = rbase + (r & 3) + 8 * (r >> 2);
                C[(size_t)row * 1024 + col] = acc[tm][tn][r] + bias;
            }
        }
    }
}

// ---------------------------------------------------------------------------
// Fallback GEMM (fp32 A converted in-kernel) for small ws_size.
// ---------------------------------------------------------------------------
__global__ __launch_bounds__(256) void gemm_fb(const float* __restrict__ A,
                                               const unsigned short* __restrict__ Wt,
                                               const float* __restrict__ beff,
                                               float* __restrict__ C) {
    __shared__ __align__(16) unsigned short As[128 * 72];
    __shared__ __align__(16) unsigned char Bs[16384];

    const int t = threadIdx.x;
    const int lane = t & 63;
    const int w = t >> 6;
    const int quad = lane >> 4;
    const int l15 = lane & 15;
    const int wm = (w & 1) * 64;
    const int wn = (w >> 1) * 64;
    const int bm = blockIdx.y * 128;
    const int bn = blockIdx.x * 128;

    floatx4 acc[4][4];
#pragma unroll
    for (int i = 0; i < 4; ++i)
#pragma unroll
        for (int j = 0; j < 4; ++j) acc[i][j] = (floatx4){0.f, 0.f, 0.f, 0.f};

    const int ar = t >> 4;
    const int ac4 = (t & 15) * 4;
    const float* Abase = A + (size_t)(bm + ar) * 1024 + ac4;
    const char* WtB = (const char*)Wt;

    for (int k0 = 0; k0 < 1024; k0 += 64) {
#pragma unroll
        for (int i = 0; i < 4; ++i) {
            int I = w * 4 + i;
            int slot = I * 64 + lane;
            int nl = slot >> 3;
            int c = (slot & 7) ^ (nl & 7);
            const char* g = WtB + (size_t)(bn + nl) * 2048 + k0 * 2 + c * 16;
            __builtin_amdgcn_global_load_lds(GLB_AS(g), LDS_AS(Bs + I * 1024), 16, 0, 0);
        }
        float4 av[8];
#pragma unroll
        for (int s = 0; s < 8; ++s)
            av[s] = *(const float4*)(Abase + (size_t)(s * 16) * 1024 + k0);
#pragma unroll
        for (int s = 0; s < 8; ++s) {
            uint2 p;
            p.x = bf16pack2(av[s].y, av[s].x);
            p.y = bf16pack2(av[s].w, av[s].z);
            *(uint2*)((char*)As + (size_t)(s * 16 + ar) * 144 + ac4 * 2) = p;
        }
        __syncthreads();
#pragma unroll
        for (int kk = 0; kk < 2; ++kk) {
            short8 af[4], bf[4];
#pragma unroll
            for (int tm = 0; tm < 4; ++tm) {
                int m = wm + tm * 16 + l15;
                af[tm] = *(const short8*)((const char*)As + (size_t)m * 144 + kk * 64 + quad * 16);
            }
#pragma unroll
            for (int tn = 0; tn < 4; ++tn) {
                int n = wn + tn * 16 + l15;
                int c = kk * 4 + quad;
                int slot = n * 8 + (c ^ (n & 7));
                bf[tn] = *(const short8*)(Bs + slot * 16);
            }
#pragma unroll
            for (int tm = 0; tm < 4; ++tm)
#pragma unroll
                for (int tn = 0; tn < 4; ++tn)
                    acc[tm][tn] = __builtin_amdgcn_mfma_f32_16x16x32_bf16(
                        af[tm], bf[tn], acc[tm][tn], 0, 0, 0);
        }
        __syncthreads();
    }
#pragma unroll
    for (int tn = 0; tn < 4; ++tn) {
        int col = bn + wn + tn * 16 + l15;
        float bias = beff[col];
#pragma unroll
        for (int tm = 0; tm < 4; ++tm) {
            int row0 = bm + wm + tm * 16 + quad * 4;
#pragma unroll
            for (int r = 0; r < 4; ++r)
                C[(size_t)(row0 + r) * 1024 + col] = acc[tm][tn][r] + bias;
        }
    }
}

extern "C" void kernel_launch(void* const* d_in, const int* in_sizes, int n_in,
                              void* d_out, int out_size, void* d_ws, size_t ws_size,
                              hipStream_t stream) {
    const float* tokens = (const float*)d_in[0];  // (4,2048,1024) fp32
    const float* W      = (const float*)d_in[1];  // (1024, 10240) fp32
    const float* b      = (const float*)d_in[2];  // (10240,) fp32
    float* out = (float*)d_out;                   // (4,2048,1024) fp32

    unsigned short* Wt = (unsigned short*)d_ws;                       // 2 MB bf16
    float* beff = (float*)((char*)d_ws + 2097152);                    // 4 KB fp32
    unsigned short* Ab = (unsigned short*)((char*)d_ws + 2101248);    // 16.8 MB bf16

    const int big_ws = ws_size >= 2101248 + (size_t)8192 * 1024 * 2;

    if (big_ws) {
        prep<<<513 + 4096, 256, 0, stream>>>(W, tokens, b, Wt, beff, (uint4*)Ab, 1);
        gemm32<<<dim3(64, 8), 256, 0, stream>>>(Ab, Wt, beff, out);
    } else {
        prep<<<513, 256, 0, stream>>>(W, tokens, b, Wt, beff, (uint4*)Ab, 0);
        gemm_fb<<<dim3(8, 64), 256, 0, stream>>>(tokens, Wt, beff, out);
    }
}